// Round 1
// baseline (416.639 us; speedup 1.0000x reference)
//
#include <hip/hip_runtime.h>
#include <hip/hip_bf16.h>

// out[b,s,n] = x[b,s,n] * w[n];  x: (4,4096,4096) fp32, w: (4096,) fp32.
// N=4096 divisible by 4 -> float4 of x aligns with float4 of w.
// Pure HBM-bound elementwise: 256 MiB in + 256 MiB out.

__global__ __launch_bounds__(256) void mulw_kernel(
    const float4* __restrict__ x4,
    const float4* __restrict__ w4,   // 1024 float4 = 4096 floats
    float4* __restrict__ out4,
    unsigned int n4)
{
    unsigned int i = blockIdx.x * blockDim.x + threadIdx.x;
    if (i >= n4) return;
    float4 v = x4[i];
    float4 w = w4[i & 1023u];  // (i*4) % 4096, in float4 units
    v.x *= w.x;
    v.y *= w.y;
    v.z *= w.z;
    v.w *= w.w;
    out4[i] = v;
}

extern "C" void kernel_launch(void* const* d_in, const int* in_sizes, int n_in,
                              void* d_out, int out_size, void* d_ws, size_t ws_size,
                              hipStream_t stream) {
    const float4* x4 = (const float4*)d_in[0];
    const float4* w4 = (const float4*)d_in[1];
    float4* out4 = (float4*)d_out;

    // total elements = 4*4096*4096 = 67,108,864 ; /4 per float4
    unsigned int n4 = (unsigned int)(out_size / 4);
    unsigned int threads = 256;
    unsigned int blocks = (n4 + threads - 1) / threads;  // 65,536

    mulw_kernel<<<blocks, threads, 0, stream>>>(x4, w4, out4, n4);
}